// Round 2
// 149.051 us; speedup vs baseline: 1.0152x; 1.0152x over previous
//
#include <hip/hip_runtime.h>
#include <stdint.h>

#define HH 512
#define WW 512
#define NIMG 64
#define OH 510
#define OW 510
#define NPB 4096                  // pair bins: 3 rows x 4 cols binary pattern = 12 bits
#define HBINS (NPB + 64)          // + 64 per-lane dummy bins
#define SEGR 16                   // output rows per big segment
#define NSEG 32
#define NREP 8                    // global hist copies: 8 * 4096 * 4B = 128 KB ws
#define BLOCK 512
#define WPB (BLOCK / 64)
#define NBLK 512
#define NWAVE (NBLK * WPB)        // 4096 waves; each does 2 big tasks (+1 seam for 1/4)
#define NBIG (NIMG * 2 * NSEG * 2)   // 8192 big wave-tasks = 2 per wave exactly
#define NSEAM (NIMG * 2 * 8)         // 1024 seam wave-tasks

typedef float f4 __attribute__((ext_vector_type(4)));

// Pinned load, flat VGPR-address form. volatile => program order kept among asm.
__device__ __forceinline__ f4 ldg4(const float* addr) {
    f4 r;
    asm volatile("global_load_dwordx4 %0, %1, off" : "=v"(r) : "v"(addr));
    return r;
}
// Wait until <=N of MY loads outstanding; "+v" tie orders consumption of x after it.
template<int N>
__device__ __forceinline__ void waitv(f4& x) {
    if      constexpr (N == 7) asm volatile("s_waitcnt vmcnt(7)" : "+v"(x));
    else if constexpr (N == 6) asm volatile("s_waitcnt vmcnt(6)" : "+v"(x));
    else if constexpr (N == 5) asm volatile("s_waitcnt vmcnt(5)" : "+v"(x));
    else if constexpr (N == 4) asm volatile("s_waitcnt vmcnt(4)" : "+v"(x));
    else if constexpr (N == 3) asm volatile("s_waitcnt vmcnt(3)" : "+v"(x));
    else if constexpr (N == 2) asm volatile("s_waitcnt vmcnt(2)" : "+v"(x));
    else if constexpr (N == 1) asm volatile("s_waitcnt vmcnt(1)" : "+v"(x));
    else                       asm volatile("s_waitcnt vmcnt(0)" : "+v"(x));
}

// Reference binarization ((x*0.5+0.5)*255 > 127.5) is exactly (x > 2^-24) in f32.
#define BINC 0x1p-24f

__device__ __forceinline__ int pack4(f4 v) {
    return (v.x > BINC) | ((v.y > BINC) << 1) | ((v.z > BINC) << 2) | ((v.w > BINC) << 3);
}

// Pair-histogram kernel. Two adjacent output codes share 6 of 9 pixels, so the
// (j,j+1) code pair is determined by a 3x4 binary block = 12-bit pair-bin.
// One ds_add per pair instead of one per code -> halves LDS atomic lane-ops,
// which counter arithmetic shows are the limiter (~1 lane-op/cy/CU).
// Bin labeling is a fixed bijection of patterns; the MSE over histograms is
// invariant under it, and the reduce kernel expands pairs -> single codes.
__global__ __launch_bounds__(BLOCK) void hist_kernel(const float* __restrict__ inp,
                                                     const float* __restrict__ tgt,
                                                     int* __restrict__ rep) {
    __shared__ int hist[HBINS];
    const int tid  = threadIdx.x;
    const int lane = tid & 63;
    const int wave = tid >> 6;

    for (int i = tid; i < HBINS; i += BLOCK) hist[i] = 0;
    __syncthreads();

    const int wid   = blockIdx.x * WPB + wave;
    const int dummy = NPB + ((lane + wave * 8) & 63);   // per-lane dummy bin
    const bool ln_ok = (lane < 63);                     // lane 63's (j=2,3) pair invalid

    #pragma unroll 1
    for (int k = 0; k < 2; ++k) {
        const int task = wid + k * NWAVE;               // two big tasks per wave
        const int tile = task & 1;
        const int seg  = (task >> 1) & 31;
        const int t    = (task >> 6) & 1;
        const int img  = task >> 7;
        const int r0   = seg * SEGR;
        const int R    = min(SEGR, OH - r0);            // 16 (seg 31: 14)
        const int c0   = tile * 256 + 4 * lane;         // lane's first col (16B aligned)
        const int sign = 1 - 2 * t;
        const float* base = (t ? tgt : inp) + (size_t)img * (HH * WW) + c0;
        auto ap = [&](int rel) { return base + (size_t)min(r0 + rel, HH - 1) * WW; };

        // ring of 8, every load consumed by a matching wait (no dead dests)
        f4 X[8];
        #pragma unroll
        for (int q = 0; q < 8; ++q) X[q] = ldg4(ap(q));

        int n0, n1, n2;
        waitv<7>(X[0]);
        { int nib = pack4(X[0]); n0 = nib | (__shfl_down(nib, 1) << 4); }
        X[0] = ldg4(ap(8));
        waitv<7>(X[1]);
        { int nib = pack4(X[1]); n1 = nib | (__shfl_down(nib, 1) << 4); }
        X[1] = ldg4(ap(9));

        // issued rows 0..9; refills rows 10..17 at o=0..7; drain o=9..15
        #define STEP(o, W) { \
            f4& Xs = X[((o) + 2) & 7]; \
            waitv<W>(Xs); \
            int nib = pack4(Xs); \
            n2 = nib | (__shfl_down(nib, 1) << 4); \
            if ((o) <= 7) Xs = ldg4(ap((o) + 10)); \
            if ((o) < R) { \
                int p01 = (n0 & 15) | ((n1 & 15) << 4) | ((n2 & 15) << 8); \
                int p23 = ((n0 >> 2) & 15) | (((n1 >> 2) & 15) << 4) \
                        | (((n2 >> 2) & 15) << 8); \
                atomicAdd(&hist[p01], sign); \
                atomicAdd(&hist[ln_ok ? p23 : dummy], sign); \
            } \
            n0 = n1; n1 = n2; }

        STEP(0, 7)  STEP(1, 7)  STEP(2, 7)  STEP(3, 7)
        STEP(4, 7)  STEP(5, 7)  STEP(6, 7)  STEP(7, 7)
        STEP(8, 7)  STEP(9, 6)  STEP(10, 5) STEP(11, 4)
        STEP(12, 3) STEP(13, 2) STEP(14, 1) STEP(15, 0)
        #undef STEP
        // vmcnt == 0 here: all loads consumed before next task's ring starts.
    }

    if ((wid & 3) == 0) {
        // ---- seam task: output cols 254,255 (inputs 254..257) pair to one bin ----
        const int idx = wid >> 2;                       // 0..1023, spread across blocks
        const int seg = idx & 7;
        const int t   = (idx >> 3) & 1;
        const int img = idx >> 4;
        const int sign = 1 - 2 * t;
        const int r   = seg * 64 + lane;
        const bool v  = (r < OH);
        const float* bp = (t ? tgt : inp) + (size_t)img * (HH * WW);
        int p[3];
        #pragma unroll
        for (int q = 0; q < 3; ++q) {
            const float* rowp = bp + (size_t)min(r + q, HH - 1) * WW;
            float2 A = *(const float2*)(rowp + 254);    // cols 254,255 (8B aligned)
            float2 B = *(const float2*)(rowp + 256);    // cols 256,257
            p[q] = (A.x > BINC) | ((A.y > BINC) << 1)
                 | ((B.x > BINC) << 2) | ((B.y > BINC) << 3);
        }
        int pair = p[0] | (p[1] << 4) | (p[2] << 8);
        atomicAdd(&hist[v ? pair : dummy], sign);
    }

    __syncthreads();
    const int rid = blockIdx.x & (NREP - 1);
    for (int i = tid; i < NPB; i += BLOCK) {            // flush real pair-bins only
        int vv = hist[i];
        if (vv) atomicAdd(&rep[rid * NPB + i], vv);
    }
}

__global__ __launch_bounds__(1024) void reduce_kernel(const int* __restrict__ rep,
                                                      float* __restrict__ out) {
    __shared__ int sh[512];          // signed single-code diff counts
    __shared__ double sd[512];
    const int tid = threadIdx.x;
    if (tid < 512) sh[tid] = 0;
    __syncthreads();

    // Expand pair-bins -> the two constituent 9-bit codes.
    // pair p: row nibbles a=p[0:4), b=p[4:8), c=p[8:12); left code uses bits 0..2
    // of each nibble, right code uses bits 1..3 (same fixed labeling as before).
    #pragma unroll
    for (int k = 0; k < NPB / 1024; ++k) {
        int p = tid + k * 1024;
        int s = 0;
        #pragma unroll
        for (int r = 0; r < NREP; ++r) s += rep[r * NPB + p];   // coalesced
        if (s) {
            int f0 = (p & 7) | (((p >> 4) & 7) << 3) | (((p >> 8) & 7) << 6);
            int f1 = ((p >> 1) & 7) | (((p >> 5) & 7) << 3) | (((p >> 9) & 7) << 6);
            atomicAdd(&sh[f0], s);
            atomicAdd(&sh[f1], s);
        }
    }
    __syncthreads();

    if (tid < 512) { double d = (double)sh[tid]; sd[tid] = d * d; }
    __syncthreads();
    for (int stp = 256; stp > 0; stp >>= 1) {
        if (tid < stp) sd[tid] += sd[tid + stp];
        __syncthreads();
    }
    if (tid == 0) {
        const double n = (double)NIMG * OH * OW;   // 16,646,400
        out[0] = (float)(sd[0] / (n * n) / 512.0 / 64.0);
    }
}

extern "C" void kernel_launch(void* const* d_in, const int* in_sizes, int n_in,
                              void* d_out, int out_size, void* d_ws, size_t ws_size,
                              hipStream_t stream) {
    const float* inp = (const float*)d_in[0];
    const float* tgt = (const float*)d_in[1];
    float* out = (float*)d_out;
    int* rep = (int*)d_ws;                      // NREP*NPB ints = 128 KB in workspace

    hipMemsetAsync(rep, 0, NREP * NPB * sizeof(int), stream);
    hist_kernel<<<NBLK, BLOCK, 0, stream>>>(inp, tgt, rep);
    reduce_kernel<<<1, 1024, 0, stream>>>(rep, out);
}